// Round 5
// baseline (377.970 us; speedup 1.0000x reference)
//
#include <hip/hip_runtime.h>

// Problem constants (from reference)
constexpr int NSAMP  = 2048;
constexpr int NDIM   = 3072;   // H*W*C = 32*32*3
constexpr int NTRANS = 3072;   // NKERNEL*NCOMP = 192*16
constexpr int NBIN   = 200;
constexpr int NCLASS = 10;
constexpr int NPATCH = 192;
constexpr int BLK    = 256;
constexpr int PER_T  = NDIM / BLK;  // 12
constexpr int DSTR   = 20;          // s_diff row stride: 16B-aligned, mod-32 varied

// ---------------- P0: ballot-based class bucketing (deterministic) ----------
__global__ __launch_bounds__(1024)
void p0_bucket(const int* __restrict__ label,
               int* __restrict__ slot,      // (NSAMP)
               int* __restrict__ cls_off)   // (NCLASS+1)
{
    __shared__ int s_lab[NSAMP];
    __shared__ int s_cnt[32][NCLASS];   // per 64-sample segment
    __shared__ int s_pre[32][NCLASS];
    __shared__ int s_tot[NCLASS];
    __shared__ int s_off[NCLASS + 1];
    const int tid  = threadIdx.x;
    const int lane = tid & 63;
    const int wv   = tid >> 6;          // 0..15

    for (int i = tid; i < NSAMP; i += 1024) s_lab[i] = label[i];
    __syncthreads();

    const unsigned long long ltmask = ((unsigned long long)1 << lane) - 1;
    int myrank[2], myc[2];
    #pragma unroll
    for (int pass = 0; pass < 2; ++pass) {
        const int n = pass * 1024 + tid;
        const int c = s_lab[n];
        myc[pass] = c;
        int r = 0;
        #pragma unroll
        for (int cls = 0; cls < NCLASS; ++cls) {
            const unsigned long long b = __ballot(c == cls);
            if (lane == 0) s_cnt[pass * 16 + wv][cls] = __popcll(b);
            if (cls == c)  r = __popcll(b & ltmask);
        }
        myrank[pass] = r;
    }
    __syncthreads();

    if (tid < 32 * NCLASS) {
        const int seg = tid & 31;
        const int cls = tid >> 5;
        int acc = 0;
        for (int s = 0; s < seg; ++s) acc += s_cnt[s][cls];
        s_pre[seg][cls] = acc;
        if (seg == 31) s_tot[cls] = acc + s_cnt[31][cls];
    }
    __syncthreads();
    if (tid == 0) {
        int a = 0;
        for (int c = 0; c < NCLASS; ++c) { s_off[c] = a; a += s_tot[c]; }
        s_off[NCLASS] = a;
    }
    __syncthreads();

    #pragma unroll
    for (int pass = 0; pass < 2; ++pass) {
        const int n   = pass * 1024 + tid;
        const int seg = pass * 16 + wv;
        const int c   = myc[pass];
        slot[n] = s_off[c] + s_pre[seg][c] + myrank[pass];
    }
    if (tid <= NCLASS) cls_off[tid] = s_off[tid];
}

// ---------------- Bt prep: Bt[p][c][i] = B[p][i][c] ----------------
__global__ __launch_bounds__(BLK)
void p_bt(const float* __restrict__ B, float* __restrict__ Bt)
{
    const int p   = blockIdx.x;
    const int tid = threadIdx.x;            // tid = i*16 + c
    const float v = B[p * 256 + tid];
    Bt[p * 256 + (tid & 15) * 16 + (tid >> 4)] = v;
}

// ---------------- A: x = data @ wT, task = (patch, c-quad) ----------------
// 16 LDS reads shared across 4 outputs (vs 16 per output before).
__global__ __launch_bounds__(BLK)
void pA_project(const float* __restrict__ data,  // (N, NDIM)
                const float* __restrict__ Bt,    // (192,16,16) transposed blocks
                const int*   __restrict__ slot,
                float* __restrict__ xbuf)        // (N, NTRANS) in slot order
{
    __shared__ float s_data[NDIM];
    const int n = blockIdx.x;
    const int tid = threadIdx.x;

    const float* drow = data + (size_t)n * NDIM;
    #pragma unroll
    for (int j = 0; j < PER_T; ++j)
        s_data[tid + BLK * j] = drow[tid + BLK * j];
    __syncthreads();

    float4* xrow4 = (float4*)(xbuf + (size_t)slot[n] * NTRANS);

    #pragma unroll
    for (int jj = 0; jj < 3; ++jj) {
        const int tau = tid + BLK * jj;     // 0..767 = p*4 + q4
        const int p   = tau >> 2;
        const int q4  = tau & 3;            // output c's: q4*4 .. q4*4+3
        const int nh  = p / 24;
        const int rem = p - nh * 24;
        const int nw  = rem / 3;
        const int ch  = rem - nw * 3;
        const int rowbase = nh * 384 + nw * 12 + ch;

        float dv[16];
        #pragma unroll
        for (int i = 0; i < 16; ++i)
            dv[i] = s_data[rowbase + (i >> 2) * 96 + (i & 3) * 3];

        const float4* Bp = (const float4*)(Bt + p * 256 + q4 * 64);
        float acc[4];
        #pragma unroll
        for (int cc = 0; cc < 4; ++cc) {
            float a = 0.f;
            #pragma unroll
            for (int q = 0; q < 4; ++q) {
                const float4 b = Bp[cc * 4 + q];
                a += b.x * dv[q * 4 + 0] + b.y * dv[q * 4 + 1]
                   + b.z * dv[q * 4 + 2] + b.w * dv[q * 4 + 3];
            }
            acc[cc] = a;
        }
        xrow4[tau] = make_float4(acc[0], acc[1], acc[2], acc[3]);
    }
}

// ---------------- B: spline, lane = sample (whole-line writes) ----------
// Block = (patch, class). Each lane owns one sample: reads/writes its own
// 64B xbuf line (proven-clean write pattern), does all 16 coords.
// kx staged in LDS for the search; ky/kd read at found bin (L1/L2-hot).
__global__ __launch_bounds__(BLK, 8)
void pB_spline(const float* __restrict__ kx,   // (10, NTRANS, NBIN)
               const float* __restrict__ ky,
               const float* __restrict__ kd,
               const int*   __restrict__ cls_off,
               float* __restrict__ xbuf,        // in: x, out: diff (in place)
               float* __restrict__ ljpart)      // (NPATCH, NSAMP)
{
    __shared__ float s_kx[16 * NBIN];           // 12.8 KB

    const int p   = blockIdx.x;   // 0..191
    const int c   = blockIdx.y;   // 0..9
    const int tid = threadIdx.x;
    const int t0  = p * 16;

    const size_t kofs = ((size_t)c * NTRANS + t0) * NBIN;
    const float4* gx = (const float4*)(kx + kofs);
    float4* lx = (float4*)s_kx;
    #pragma unroll 1
    for (int i = tid; i < 16 * NBIN / 4; i += BLK) lx[i] = gx[i];
    __syncthreads();

    const float* kyp = ky + kofs;
    const float* kdp = kd + kofs;

    const int beg = cls_off[c];
    const int end = cls_off[c + 1];

    for (int sbase = beg; sbase < end; sbase += BLK) {
        const int sl = sbase + tid;
        if (sl < end) {
            float* xrow = xbuf + (size_t)sl * NTRANS + t0;  // 64B-aligned line
            const float4 v0 = ((const float4*)xrow)[0];
            const float4 v1 = ((const float4*)xrow)[1];
            const float4 v2 = ((const float4*)xrow)[2];
            const float4 v3 = ((const float4*)xrow)[3];
            float xs[16] = {v0.x, v0.y, v0.z, v0.w, v1.x, v1.y, v1.z, v1.w,
                            v2.x, v2.y, v2.z, v2.w, v3.x, v3.y, v3.z, v3.w};

            float lj_sum = 0.f;
            #pragma unroll
            for (int j = 0; j < 16; ++j) {
                const float* xx  = &s_kx[j * NBIN];
                const float* yyg = kyp + j * NBIN;
                const float* ddg = kdp + j * NBIN;
                const float x  = xs[j];
                const float lo = xx[0];
                const float hi = xx[NBIN - 1];

                float y, lj;
                if (x < lo) {
                    const float d0 = ddg[0];
                    y  = yyg[0] + (x - lo) * d0;
                    lj = __logf(d0);
                } else if (x > hi) {
                    const float dK = ddg[NBIN - 1];
                    y  = yyg[NBIN - 1] + (x - hi) * dK;
                    lj = __logf(dK);
                } else {
                    int klo = 0, khi = NBIN;
                    #pragma unroll
                    for (int it = 0; it < 8; ++it) {
                        const int mid = (klo + khi) >> 1;
                        const bool le = (xx[mid] <= x);
                        klo = le ? mid : klo;
                        khi = le ? khi : mid;
                    }
                    int k = klo;
                    if (k > NBIN - 2) k = NBIN - 2;

                    const float xk = xx[k], xk1 = xx[k + 1];
                    const float yk = yyg[k], yk1 = yyg[k + 1];
                    const float dk = ddg[k], dk1 = ddg[k + 1];

                    const float wdt     = xk1 - xk;
                    const float inv_wdt = __fdividef(1.f, wdt);
                    const float dy      = yk1 - yk;
                    const float s       = dy * inv_wdt;
                    const float xi      = (x - xk) * inv_wdt;
                    const float om      = 1.f - xi;
                    const float denom   = s + (dk1 + dk - 2.f * s) * xi * om;
                    const float r       = __fdividef(1.f, denom);
                    const float num     = dy * (s * xi * xi + dk * xi * om);
                    y = yk + num * r;
                    const float Nq = dk1 * xi * xi + 2.f * s * xi * om + dk * om * om;
                    const float t2 = s * r;
                    lj = __logf(t2 * t2 * Nq);   // 2log(s)+log(Nq)-2log(denom)
                }
                xs[j] = y - x;
                lj_sum += lj;
            }

            ((float4*)xrow)[0] = make_float4(xs[0],  xs[1],  xs[2],  xs[3]);
            ((float4*)xrow)[1] = make_float4(xs[4],  xs[5],  xs[6],  xs[7]);
            ((float4*)xrow)[2] = make_float4(xs[8],  xs[9],  xs[10], xs[11]);
            ((float4*)xrow)[3] = make_float4(xs[12], xs[13], xs[14], xs[15]);
            ljpart[(size_t)p * NSAMP + sl] = lj_sum;
        }
    }
}

// ---------------- ljreduce: logj_slot[sl] = sum_p ljpart[p][sl] ------------
__global__ __launch_bounds__(BLK)
void p_ljred(const float* __restrict__ ljpart,
             float* __restrict__ logj_slot)
{
    const int sl = blockIdx.x * BLK + threadIdx.x;
    float a0 = 0.f, a1 = 0.f, a2 = 0.f, a3 = 0.f;
    #pragma unroll 1
    for (int g = 0; g < NPATCH; g += 4) {
        a0 += ljpart[(size_t)(g + 0) * NSAMP + sl];
        a1 += ljpart[(size_t)(g + 1) * NSAMP + sl];
        a2 += ljpart[(size_t)(g + 2) * NSAMP + sl];
        a3 += ljpart[(size_t)(g + 3) * NSAMP + sl];
    }
    logj_slot[sl] = (a0 + a1) + (a2 + a3);
}

// ---------------- C: out = data + diff @ wT^T (b128 LDS reads) -------------
__global__ __launch_bounds__(BLK)
void pC_recon(const float* __restrict__ data,
              const float* __restrict__ B,
              const int*   __restrict__ slot,
              const float* __restrict__ xbuf,      // diff, slot order
              const float* __restrict__ logj_slot,
              float* __restrict__ out,
              float* __restrict__ logj)
{
    __shared__ float s_diff[NPATCH * DSTR];   // 15.4 KB, rows 16B-aligned
    const int n   = blockIdx.x;
    const int tid = threadIdx.x;
    const int sl  = slot[n];

    const float4* drow_diff = (const float4*)(xbuf + (size_t)sl * NTRANS);
    for (int i = tid; i < NTRANS / 4; i += BLK) {
        const float4 v = drow_diff[i];
        const int t = i * 4;                       // (t&15) in {0,4,8,12}
        *(float4*)&s_diff[(t >> 4) * DSTR + (t & 15)] = v;
    }
    if (tid == 0) logj[n] = logj_slot[sl];
    __syncthreads();

    const float* drow = data + (size_t)n * NDIM;
    float* orow = out + (size_t)n * NDIM;
    #pragma unroll 1
    for (int j = 0; j < PER_T; ++j) {
        const int d  = tid + BLK * j;
        const int ch = d % 3;
        const int hw = d / 3;
        const int w  = hw & 31;
        const int h  = hw >> 5;
        const int p  = ((h >> 2) * 8 + (w >> 2)) * 3 + ch;
        const int i  = (h & 3) * 4 + (w & 3);

        const float4* Bp4 = (const float4*)(B + p * 256 + i * 16);
        const float4* dp4 = (const float4*)&s_diff[p * DSTR];
        float acc = drow[d];
        #pragma unroll
        for (int q = 0; q < 4; ++q) {
            const float4 b = Bp4[q];
            const float4 dd = dp4[q];
            acc += b.x * dd.x + b.y * dd.y + b.z * dd.z + b.w * dd.w;
        }
        orow[d] = acc;
    }
}

extern "C" void kernel_launch(void* const* d_in, const int* in_sizes, int n_in,
                              void* d_out, int out_size, void* d_ws, size_t ws_size,
                              hipStream_t stream) {
    const float* data  = (const float*)d_in[0];
    const int*   label = (const int*)  d_in[1];
    const float* B     = (const float*)d_in[2];
    const float* kx    = (const float*)d_in[3];
    const float* ky    = (const float*)d_in[4];
    const float* kd    = (const float*)d_in[5];

    float* out  = (float*)d_out;
    float* logj = (float*)d_out + (size_t)NSAMP * NDIM;

    // ws layout
    char* ws = (char*)d_ws;
    size_t off = 0;
    float* xbuf      = (float*)(ws + off); off += (size_t)NSAMP * NTRANS * 4;   // 25.2 MB
    float* ljpart    = (float*)(ws + off); off += (size_t)NPATCH * NSAMP * 4;   // 1.6 MB
    float* Bt        = (float*)(ws + off); off += (size_t)NPATCH * 256 * 4;     // 196 KB
    float* logj_slot = (float*)(ws + off); off += NSAMP * 4;
    int*   slot      = (int*)  (ws + off); off += NSAMP * 4;
    int*   cls_off   = (int*)  (ws + off); off += 64;

    p0_bucket <<<1, 1024, 0, stream>>>(label, slot, cls_off);
    p_bt      <<<NPATCH, BLK, 0, stream>>>(B, Bt);
    pA_project<<<NSAMP, BLK, 0, stream>>>(data, Bt, slot, xbuf);
    dim3 gridB(NPATCH, NCLASS);
    pB_spline <<<gridB, BLK, 0, stream>>>(kx, ky, kd, cls_off, xbuf, ljpart);
    p_ljred   <<<NSAMP / BLK, BLK, 0, stream>>>(ljpart, logj_slot);
    pC_recon  <<<NSAMP, BLK, 0, stream>>>(data, B, slot, xbuf, logj_slot, out, logj);
}

// Round 6
// 264.483 us; speedup vs baseline: 1.4291x; 1.4291x over previous
//
#include <hip/hip_runtime.h>

// Problem constants (from reference)
constexpr int NSAMP  = 2048;
constexpr int NDIM   = 3072;   // H*W*C = 32*32*3
constexpr int NTRANS = 3072;   // NKERNEL*NCOMP = 192*16
constexpr int NBIN   = 200;
constexpr int NCLASS = 10;
constexpr int NPATCH = 192;
constexpr int BLK    = 256;
constexpr int PER_T  = NDIM / BLK;  // 12
constexpr int DSTR   = 20;          // s_diff row stride: 16B-aligned

// xb layout: xb[p][sl][c] -- (NPATCH, NSAMP, 16). One 64B line per (p,sl).

// ---------------- P0: ballot-based class bucketing (deterministic) ----------
__global__ __launch_bounds__(1024)
void p0_bucket(const int* __restrict__ label,
               int* __restrict__ slot,      // (NSAMP)
               int* __restrict__ cls_off)   // (NCLASS+1)
{
    __shared__ int s_lab[NSAMP];
    __shared__ int s_cnt[32][NCLASS];
    __shared__ int s_pre[32][NCLASS];
    __shared__ int s_tot[NCLASS];
    __shared__ int s_off[NCLASS + 1];
    const int tid  = threadIdx.x;
    const int lane = tid & 63;
    const int wv   = tid >> 6;

    for (int i = tid; i < NSAMP; i += 1024) s_lab[i] = label[i];
    __syncthreads();

    const unsigned long long ltmask = ((unsigned long long)1 << lane) - 1;
    int myrank[2], myc[2];
    #pragma unroll
    for (int pass = 0; pass < 2; ++pass) {
        const int n = pass * 1024 + tid;
        const int c = s_lab[n];
        myc[pass] = c;
        int r = 0;
        #pragma unroll
        for (int cls = 0; cls < NCLASS; ++cls) {
            const unsigned long long b = __ballot(c == cls);
            if (lane == 0) s_cnt[pass * 16 + wv][cls] = __popcll(b);
            if (cls == c)  r = __popcll(b & ltmask);
        }
        myrank[pass] = r;
    }
    __syncthreads();

    if (tid < 32 * NCLASS) {
        const int seg = tid & 31;
        const int cls = tid >> 5;
        int acc = 0;
        for (int s = 0; s < seg; ++s) acc += s_cnt[s][cls];
        s_pre[seg][cls] = acc;
        if (seg == 31) s_tot[cls] = acc + s_cnt[31][cls];
    }
    __syncthreads();
    if (tid == 0) {
        int a = 0;
        for (int c = 0; c < NCLASS; ++c) { s_off[c] = a; a += s_tot[c]; }
        s_off[NCLASS] = a;
    }
    __syncthreads();

    #pragma unroll
    for (int pass = 0; pass < 2; ++pass) {
        const int n   = pass * 1024 + tid;
        const int seg = pass * 16 + wv;
        const int c   = myc[pass];
        slot[n] = s_off[c] + s_pre[seg][c] + myrank[pass];
    }
    if (tid <= NCLASS) cls_off[tid] = s_off[tid];
}

// ---------------- Bt prep: Bt[p][c][i] = B[p][i][c] ----------------
__global__ __launch_bounds__(BLK)
void p_bt(const float* __restrict__ B, float* __restrict__ Bt)
{
    const int p   = blockIdx.x;
    const int tid = threadIdx.x;            // tid = i*16 + c
    const float v = B[p * 256 + tid];
    Bt[p * 256 + (tid & 15) * 16 + (tid >> 4)] = v;
}

// ---------------- A: x = data @ wT -> blocked layout ----------------
// Task = (patch, c-quad); quad-lanes (same p) fill one full 64B line.
__global__ __launch_bounds__(BLK)
void pA_project(const float* __restrict__ data,  // (N, NDIM)
                const float* __restrict__ Bt,    // (192,16,16) transposed blocks
                const int*   __restrict__ slot,
                float* __restrict__ xb)          // (NPATCH, NSAMP, 16)
{
    __shared__ float s_data[NDIM];
    const int n = blockIdx.x;
    const int tid = threadIdx.x;

    const float* drow = data + (size_t)n * NDIM;
    #pragma unroll
    for (int j = 0; j < PER_T; ++j)
        s_data[tid + BLK * j] = drow[tid + BLK * j];
    __syncthreads();

    const int sl = slot[n];

    #pragma unroll
    for (int jj = 0; jj < 3; ++jj) {
        const int tau = tid + BLK * jj;     // 0..767 = p*4 + q4
        const int p   = tau >> 2;
        const int q4  = tau & 3;            // coords q4*4 .. q4*4+3
        const int nh  = p / 24;
        const int rem = p - nh * 24;
        const int nw  = rem / 3;
        const int ch  = rem - nw * 3;
        const int rowbase = nh * 384 + nw * 12 + ch;

        float dv[16];
        #pragma unroll
        for (int i = 0; i < 16; ++i)
            dv[i] = s_data[rowbase + (i >> 2) * 96 + (i & 3) * 3];

        const float4* Bp = (const float4*)(Bt + p * 256 + q4 * 64);
        float acc[4];
        #pragma unroll
        for (int cc = 0; cc < 4; ++cc) {
            float a = 0.f;
            #pragma unroll
            for (int q = 0; q < 4; ++q) {
                const float4 b = Bp[cc * 4 + q];
                a += b.x * dv[q * 4 + 0] + b.y * dv[q * 4 + 1]
                   + b.z * dv[q * 4 + 2] + b.w * dv[q * 4 + 3];
            }
            acc[cc] = a;
        }
        // quad-lanes write one contiguous 64B line
        *((float4*)(xb + ((size_t)p * NSAMP + sl) * 16) + q4) =
            make_float4(acc[0], acc[1], acc[2], acc[3]);
    }
}

// ---------------- B: spline, thread = (sample, coord-quad) ----------------
// Block = (patch, class). Working set contiguous: xb[p][beg..end][0..15].
// One float4 load, 4 evals, one float4 store per thread-pass.
__global__ __launch_bounds__(BLK, 8)
void pB_spline(const float* __restrict__ kx,   // (10, NTRANS, NBIN)
               const float* __restrict__ ky,
               const float* __restrict__ kd,
               const int*   __restrict__ cls_off,
               float* __restrict__ xb,          // in: x, out: diff (in place)
               float* __restrict__ ljpart)      // (NPATCH, NSAMP)
{
    __shared__ float s_kx[16 * NBIN];           // 12.8 KB

    const int p   = blockIdx.x;   // 0..191
    const int c   = blockIdx.y;   // 0..9
    const int tid = threadIdx.x;
    const int t0  = p * 16;

    const size_t kofs = ((size_t)c * NTRANS + t0) * NBIN;
    const float4* gx = (const float4*)(kx + kofs);
    float4* lx = (float4*)s_kx;
    #pragma unroll 1
    for (int i = tid; i < 16 * NBIN / 4; i += BLK) lx[i] = gx[i];
    __syncthreads();

    const int qq  = tid & 3;      // coord quad
    const int sid = tid >> 2;     // 0..63 sample within pass
    const float* sxx = s_kx + qq * 4 * NBIN;
    const float* kyp = ky + kofs + (size_t)(qq * 4) * NBIN;
    const float* kdp = kd + kofs + (size_t)(qq * 4) * NBIN;

    const int beg = cls_off[c];
    const int end = cls_off[c + 1];

    for (int s0 = beg; s0 < end; s0 += 64) {
        const int sl = s0 + sid;            // quad-uniform
        if (sl < end) {
            float4* line = (float4*)(xb + ((size_t)p * NSAMP + sl) * 16) + qq;
            const float4 v = *line;
            float xs[4] = {v.x, v.y, v.z, v.w};

            float lj_sum = 0.f;
            #pragma unroll
            for (int j = 0; j < 4; ++j) {
                const float* xx  = sxx + j * NBIN;
                const float* yyg = kyp + j * NBIN;
                const float* ddg = kdp + j * NBIN;
                const float x  = xs[j];
                const float lo = xx[0];
                const float hi = xx[NBIN - 1];

                float y, lj;
                if (x < lo) {
                    const float d0 = ddg[0];
                    y  = yyg[0] + (x - lo) * d0;
                    lj = __logf(d0);
                } else if (x > hi) {
                    const float dK = ddg[NBIN - 1];
                    y  = yyg[NBIN - 1] + (x - hi) * dK;
                    lj = __logf(dK);
                } else {
                    int klo = 0, khi = NBIN;
                    #pragma unroll
                    for (int it = 0; it < 8; ++it) {
                        const int mid = (klo + khi) >> 1;
                        const bool le = (xx[mid] <= x);
                        klo = le ? mid : klo;
                        khi = le ? khi : mid;
                    }
                    int k = klo;
                    if (k > NBIN - 2) k = NBIN - 2;

                    const float xk = xx[k], xk1 = xx[k + 1];
                    const float yk = yyg[k], yk1 = yyg[k + 1];
                    const float dk = ddg[k], dk1 = ddg[k + 1];

                    const float wdt     = xk1 - xk;
                    const float inv_wdt = __fdividef(1.f, wdt);
                    const float dy      = yk1 - yk;
                    const float s       = dy * inv_wdt;
                    const float xi      = (x - xk) * inv_wdt;
                    const float om      = 1.f - xi;
                    const float denom   = s + (dk1 + dk - 2.f * s) * xi * om;
                    const float r       = __fdividef(1.f, denom);
                    const float num     = dy * (s * xi * xi + dk * xi * om);
                    y = yk + num * r;
                    const float Nq = dk1 * xi * xi + 2.f * s * xi * om + dk * om * om;
                    const float t2 = s * r;
                    lj = __logf(t2 * t2 * Nq);   // 2log(s)+log(Nq)-2log(denom)
                }
                xs[j] = y - x;
                lj_sum += lj;
            }

            *line = make_float4(xs[0], xs[1], xs[2], xs[3]);

            // quad reduction (all quad lanes active: guard is quad-uniform)
            lj_sum += __shfl_xor(lj_sum, 1);
            lj_sum += __shfl_xor(lj_sum, 2);
            if (qq == 0) ljpart[(size_t)p * NSAMP + sl] = lj_sum;
        }
    }
}

// ---------------- ljreduce: logj_slot[sl] = sum_p ljpart[p][sl] ------------
__global__ __launch_bounds__(BLK)
void p_ljred(const float* __restrict__ ljpart,
             float* __restrict__ logj_slot)
{
    const int sl = blockIdx.x * BLK + threadIdx.x;
    float a0 = 0.f, a1 = 0.f, a2 = 0.f, a3 = 0.f;
    #pragma unroll 1
    for (int g = 0; g < NPATCH; g += 4) {
        a0 += ljpart[(size_t)(g + 0) * NSAMP + sl];
        a1 += ljpart[(size_t)(g + 1) * NSAMP + sl];
        a2 += ljpart[(size_t)(g + 2) * NSAMP + sl];
        a3 += ljpart[(size_t)(g + 3) * NSAMP + sl];
    }
    logj_slot[sl] = (a0 + a1) + (a2 + a3);
}

// ---------------- C: out = data + diff @ wT^T ----------------
__global__ __launch_bounds__(BLK)
void pC_recon(const float* __restrict__ data,
              const float* __restrict__ B,
              const int*   __restrict__ slot,
              const float* __restrict__ xb,        // diff, blocked layout
              const float* __restrict__ logj_slot,
              float* __restrict__ out,
              float* __restrict__ logj)
{
    __shared__ float s_diff[NPATCH * DSTR];   // 15.4 KB
    const int n   = blockIdx.x;
    const int tid = threadIdx.x;
    const int sl  = slot[n];

    // gather this sample's 192 lines (each read exactly once, full 64B)
    #pragma unroll
    for (int jj = 0; jj < 3; ++jj) {
        const int i  = tid + BLK * jj;      // 0..767 = pp*4 + q
        const int pp = i >> 2;
        const int q  = i & 3;
        const float4 v = *((const float4*)(xb + ((size_t)pp * NSAMP + sl) * 16) + q);
        *(float4*)&s_diff[pp * DSTR + q * 4] = v;
    }
    if (tid == 0) logj[n] = logj_slot[sl];
    __syncthreads();

    const float* drow = data + (size_t)n * NDIM;
    float* orow = out + (size_t)n * NDIM;
    #pragma unroll 1
    for (int j = 0; j < PER_T; ++j) {
        const int d  = tid + BLK * j;
        const int ch = d % 3;
        const int hw = d / 3;
        const int w  = hw & 31;
        const int h  = hw >> 5;
        const int p  = ((h >> 2) * 8 + (w >> 2)) * 3 + ch;
        const int i  = (h & 3) * 4 + (w & 3);

        const float4* Bp4 = (const float4*)(B + p * 256 + i * 16);
        const float4* dp4 = (const float4*)&s_diff[p * DSTR];
        float acc = drow[d];
        #pragma unroll
        for (int q = 0; q < 4; ++q) {
            const float4 b = Bp4[q];
            const float4 dd = dp4[q];
            acc += b.x * dd.x + b.y * dd.y + b.z * dd.z + b.w * dd.w;
        }
        orow[d] = acc;
    }
}

extern "C" void kernel_launch(void* const* d_in, const int* in_sizes, int n_in,
                              void* d_out, int out_size, void* d_ws, size_t ws_size,
                              hipStream_t stream) {
    const float* data  = (const float*)d_in[0];
    const int*   label = (const int*)  d_in[1];
    const float* B     = (const float*)d_in[2];
    const float* kx    = (const float*)d_in[3];
    const float* ky    = (const float*)d_in[4];
    const float* kd    = (const float*)d_in[5];

    float* out  = (float*)d_out;
    float* logj = (float*)d_out + (size_t)NSAMP * NDIM;

    // ws layout
    char* ws = (char*)d_ws;
    size_t off = 0;
    float* xb        = (float*)(ws + off); off += (size_t)NPATCH * NSAMP * 16 * 4; // 25.2 MB
    float* ljpart    = (float*)(ws + off); off += (size_t)NPATCH * NSAMP * 4;      // 1.6 MB
    float* Bt        = (float*)(ws + off); off += (size_t)NPATCH * 256 * 4;        // 196 KB
    float* logj_slot = (float*)(ws + off); off += NSAMP * 4;
    int*   slot      = (int*)  (ws + off); off += NSAMP * 4;
    int*   cls_off   = (int*)  (ws + off); off += 64;

    p0_bucket <<<1, 1024, 0, stream>>>(label, slot, cls_off);
    p_bt      <<<NPATCH, BLK, 0, stream>>>(B, Bt);
    pA_project<<<NSAMP, BLK, 0, stream>>>(data, Bt, slot, xb);
    dim3 gridB(NPATCH, NCLASS);
    pB_spline <<<gridB, BLK, 0, stream>>>(kx, ky, kd, cls_off, xb, ljpart);
    p_ljred   <<<NSAMP / BLK, BLK, 0, stream>>>(ljpart, logj_slot);
    pC_recon  <<<NSAMP, BLK, 0, stream>>>(data, B, slot, xb, logj_slot, out, logj);
}